// Round 5
// baseline (329.589 us; speedup 1.0000x reference)
//
#include <hip/hip_runtime.h>
#include <hip/hip_bf16.h>

#define B_ 32
#define S_ 64
#define H_ 300
#define H2_ 600
#define L_ 20
#define ROW_ 160                    // 8 pieces * 20
#define OUTQ_OFF ((size_t)B_ * S_ * ROW_)
#define NEG_INF -3.402823466e38f

// ---------------- K0: w^2 table [widx][l][h]
__global__ void k_w2(const float* __restrict__ Wf, float* __restrict__ w2) {
  int i = blockIdx.x * 256 + threadIdx.x;
  if (i < 8 * L_ * H_) { float v = Wf[i]; w2[i] = v * v; }
}

// ---------------- K1: plain cosine matrix per (b,dir) + fp64 row/col sums.
// thread t -> q=lane=t&63, p=(t>>6)+4k for k in [0,16).
__global__ __launch_bounds__(256) void k_cos(const float* __restrict__ P,
                                             const float* __restrict__ Q,
                                             float* __restrict__ cosM,
                                             float* __restrict__ sum_p,
                                             float* __restrict__ sum_q) {
  int bd = blockIdx.x;
  int b = bd >> 1, dir = bd & 1;
  __shared__ float xp[S_][101];
  __shared__ float xq[S_][101];
  __shared__ float pn[S_], qn[S_];
  __shared__ float cosL[S_][S_ + 1];
  int t = threadIdx.x;
  int w = t >> 6, lane = t & 63;
  float dot[16];
#pragma unroll
  for (int k = 0; k < 16; ++k) dot[k] = 0.f;
  float np2 = 0.f, nq2 = 0.f;
  const float* Pb = P + (size_t)b * S_ * H2_ + dir * H_;
  const float* Qb = Q + (size_t)b * S_ * H2_ + dir * H_;
  for (int c0 = 0; c0 < H_; c0 += 100) {
    __syncthreads();
    for (int idx = t; idx < S_ * 100; idx += 256) {
      int s = idx / 100, hh = idx - s * 100;
      xp[s][hh] = Pb[(size_t)s * H2_ + c0 + hh];
      xq[s][hh] = Qb[(size_t)s * H2_ + c0 + hh];
    }
    __syncthreads();
    for (int hh = 0; hh < 100; ++hh) {
      float qv = xq[lane][hh];
#pragma unroll
      for (int k = 0; k < 16; ++k) dot[k] = fmaf(xp[w + 4 * k][hh], qv, dot[k]);
    }
    if (t < S_) {
      for (int hh = 0; hh < 100; ++hh) { float v = xp[t][hh]; np2 = fmaf(v, v, np2); }
    } else if (t < 2 * S_) {
      int s2 = t - S_;
      for (int hh = 0; hh < 100; ++hh) { float v = xq[s2][hh]; nq2 = fmaf(v, v, nq2); }
    }
  }
  if (t < S_) pn[t] = sqrtf(np2);
  else if (t < 2 * S_) qn[t - S_] = sqrtf(nq2);
  __syncthreads();
  float* cm = cosM + (size_t)bd * S_ * S_;
#pragma unroll
  for (int k = 0; k < 16; ++k) {
    int p = w + 4 * k;
    float c = dot[k] / (pn[p] * qn[lane]);   // no EPS in reference attentive cos
    cosL[p][lane] = c;
    cm[p * S_ + lane] = c;
  }
  __syncthreads();
  if (t < S_) {            // sum over p at q=t  (cos.sum(axis=1))
    double acc = 0.0;
    for (int p = 0; p < S_; ++p) acc += (double)cosL[p][t];
    sum_p[bd * S_ + t] = (float)acc;
  } else if (t < 2 * S_) { // sum over q at p=t-64  (cos.sum(axis=2))
    int r = t - S_;
    double acc = 0.0;
    for (int q = 0; q < S_; ++q) acc += (double)cosL[r][q];
    sum_q[bd * S_ + r] = (float)acc;
  }
}

// ---------------- K2: maxpool matching, one block per (b,dir,l) -> pieces 2,3.
__global__ __launch_bounds__(256) void k_maxpool(const float* __restrict__ P,
                                                 const float* __restrict__ Q,
                                                 const float* __restrict__ w2,
                                                 float* __restrict__ out) {
  int l = blockIdx.x % L_;
  int bd = blockIdx.x / L_;
  int b = bd >> 1, dir = bd & 1;
  int t = threadIdx.x;
  int w = t >> 6, lane = t & 63;
  __shared__ float xp[S_][75];
  __shared__ float xq[S_][75];
  __shared__ float w2s[H_];
  __shared__ float pn[S_], qn[S_];
  __shared__ float cosT[S_][S_ + 1];
  const float* w2g = w2 + (size_t)(2 + dir) * L_ * H_ + (size_t)l * H_;
  for (int idx = t; idx < H_; idx += 256) w2s[idx] = w2g[idx];
  float dot[16];
#pragma unroll
  for (int k = 0; k < 16; ++k) dot[k] = 0.f;
  float np2 = 0.f, nq2 = 0.f;
  const float* Pb = P + (size_t)b * S_ * H2_ + dir * H_;
  const float* Qb = Q + (size_t)b * S_ * H2_ + dir * H_;
  for (int c0 = 0; c0 < H_; c0 += 75) {
    __syncthreads();
    for (int idx = t; idx < S_ * 75; idx += 256) {
      int s = idx / 75, hh = idx - s * 75;
      xp[s][hh] = Pb[(size_t)s * H2_ + c0 + hh];
      xq[s][hh] = Qb[(size_t)s * H2_ + c0 + hh];
    }
    __syncthreads();
    for (int hh = 0; hh < 75; ++hh) {
      float wq = w2s[c0 + hh] * xq[lane][hh];
#pragma unroll
      for (int k = 0; k < 16; ++k) dot[k] = fmaf(xp[w + 4 * k][hh], wq, dot[k]);
    }
    if (t < S_) {
      for (int hh = 0; hh < 75; ++hh) { float v = xp[t][hh]; np2 = fmaf(w2s[c0 + hh] * v, v, np2); }
    } else if (t < 2 * S_) {
      int s2 = t - S_;
      for (int hh = 0; hh < 75; ++hh) { float v = xq[s2][hh]; nq2 = fmaf(w2s[c0 + hh] * v, v, nq2); }
    }
  }
  if (t < S_) pn[t] = sqrtf(np2);
  else if (t < 2 * S_) qn[t - S_] = sqrtf(nq2);
  __syncthreads();
#pragma unroll
  for (int k = 0; k < 16; ++k) {
    int p = w + 4 * k;
    cosT[p][lane] = dot[k] / (pn[p] * qn[lane]);   // no EPS in reference maxpool
  }
  __syncthreads();
  if (t < S_) {            // out_p[s=t] = max over q
    float m = NEG_INF;
    for (int q = 0; q < S_; ++q) m = fmaxf(m, cosT[t][q]);
    out[((size_t)b * S_ + t) * ROW_ + (2 + dir) * L_ + l] = m;
  } else if (t < 2 * S_) { // out_q[s] = max over p
    int s2 = t - S_;
    float m = NEG_INF;
    for (int p = 0; p < S_; ++p) m = fmaxf(m, cosT[p][s2]);
    out[OUTQ_OFF + ((size_t)b * S_ + s2) * ROW_ + (2 + dir) * L_ + l] = m;
  }
}

// ---------------- K3: FUSED attentive vectors + full/attentive outputs.
// One block per (bd, s). Attention vectors live only in LDS.
__global__ __launch_bounds__(256) void k_outs(const float* __restrict__ P,
                                              const float* __restrict__ Q,
                                              const float* __restrict__ w2,
                                              const float* __restrict__ cosM,
                                              const float* __restrict__ sum_p,
                                              const float* __restrict__ sum_q,
                                              float* __restrict__ out) {
  int bd = blockIdx.x >> 6;
  int s = blockIdx.x & 63;
  int b = bd >> 1, dir = bd & 1;
  int t = threadIdx.x;
  __shared__ float cosRow[S_];   // cos[s][q]
  __shared__ float cosCol[S_];   // cos[p][s]
  __shared__ float v8[8][H_];    // 0 xP, 1 xQ, 2 tQ, 3 tP, 4 qvm, 5 pvm, 6 qvx, 7 pvx
  __shared__ float sps, sqs;
  const float* cm = cosM + (size_t)bd * S_ * S_;
  if (t < S_) cosRow[t] = cm[s * S_ + t];
  else if (t < 2 * S_) cosCol[t - S_] = cm[(t - S_) * S_ + s];
  else if (t == 128) sps = sum_p[bd * S_ + s];   // sum over p of cos[p][s]
  else if (t == 129) sqs = sum_q[bd * S_ + s];   // sum over q of cos[s][q]
  int tgt = dir ? 0 : S_ - 1;
  const float* Pb = P + (size_t)b * S_ * H2_ + dir * H_;
  const float* Qb = Q + (size_t)b * S_ * H2_ + dir * H_;
  for (int idx = t; idx < 4 * H_; idx += 256) {
    int a = idx / H_, h = idx - a * H_;
    float v;
    switch (a) {
      case 0:  v = Pb[(size_t)s * H2_ + h]; break;
      case 1:  v = Qb[(size_t)s * H2_ + h]; break;
      case 2:  v = Qb[(size_t)tgt * H2_ + h]; break;
      default: v = Pb[(size_t)tgt * H2_ + h]; break;
    }
    v8[a][h] = v;
  }
  __syncthreads();
  // attention vectors for this s: qv* need cos row s, pv* need cos col s
  for (int h = t; h < H_; h += 256) {
    float am_p = 0.f, am_q = 0.f, ax_p = NEG_INF, ax_q = NEG_INF;
    for (int k = 0; k < S_; ++k) {
      float pv = Pb[(size_t)k * H2_ + h];
      float qv = Qb[(size_t)k * H2_ + h];
      float t1 = pv * cosCol[k];   // p_vec candidates at q=s
      am_p += t1; ax_p = fmaxf(ax_p, t1);
      float t2 = qv * cosRow[k];   // q_vec candidates at p=s
      am_q += t2; ax_q = fmaxf(ax_q, t2);
    }
    v8[4][h] = am_q / sqs;   // qvm = q_vec[p=s]
    v8[5][h] = am_p / sps;   // pvm = p_vec[q=s]
    v8[6][h] = ax_q;         // qvx
    v8[7][h] = ax_p;         // pvx
  }
  __syncthreads();
  if (t < 120) {
    int pr = t / L_, l = t - pr * L_;
    // pr: 0 p.tq W0  1 q.tp W0  2 p.qvm W4  3 q.pvm W4  4 p.qvx W6  5 q.pvx W6
    const int yi_[6] = {2, 3, 4, 5, 6, 7};
    const int wb_[6] = {0, 0, 4, 4, 6, 6};
    const float* x = v8[pr & 1];
    const float* y = v8[yi_[pr]];
    int widx = wb_[pr] + dir;
    const float* wp = w2 + (size_t)widx * (L_ * H_) + (size_t)l * H_;
    float a1 = 0.f, a2 = 0.f, a3 = 0.f;
    for (int h = 0; h < H_; ++h) {
      float wv = wp[h];
      float xx = x[h], yy = y[h];
      float wx = wv * xx;
      a1 = fmaf(wx, yy, a1);
      a2 = fmaf(wx, xx, a2);
      a3 = fmaf(wv * yy, yy, a3);
    }
    float den = fmaxf(sqrtf(a2) * sqrtf(a3), 1e-8f);   // EPS per _mp_cos
    float c = a1 / den;
    size_t base = ((pr & 1) ? OUTQ_OFF : 0) + ((size_t)b * S_ + s) * ROW_;
    out[base + (size_t)(wb_[pr] + dir) * L_ + l] = c;
  }
}

extern "C" void kernel_launch(void* const* d_in, const int* in_sizes, int n_in,
                              void* d_out, int out_size, void* d_ws, size_t ws_size,
                              hipStream_t stream) {
  (void)out_size; (void)ws_size;
  // W is the unique 48000-element input; p,q in dict order among the rest.
  int iw = 2;
  for (int i = 0; i < n_in; ++i) if (in_sizes[i] == 8 * L_ * H_) iw = i;
  int io[2] = {0, 1}, k = 0;
  for (int i = 0; i < n_in && k < 2; ++i) if (i != iw) io[k++] = i;
  const float* P  = (const float*)d_in[io[0]];
  const float* Q  = (const float*)d_in[io[1]];
  const float* Wf = (const float*)d_in[iw];
  float* out = (float*)d_out;   // reference output dtype is float32 -> float*

  float* ws = (float*)d_ws;     // 1.27 MB total
  float* w2    = ws;                // 48000
  float* cosM  = w2 + 48000;        // 262144
  float* sum_p = cosM + 262144;     // 4096
  float* sum_q = sum_p + 4096;      // 4096

  k_w2<<<(8 * L_ * H_ + 255) / 256, 256, 0, stream>>>(Wf, w2);
  k_cos<<<B_ * 2, 256, 0, stream>>>(P, Q, cosM, sum_p, sum_q);
  k_maxpool<<<B_ * 2 * L_, 256, 0, stream>>>(P, Q, w2, out);
  k_outs<<<B_ * 2 * S_, 256, 0, stream>>>(P, Q, w2, cosM, sum_p, sum_q, out);
}

// Round 6
// 274.069 us; speedup vs baseline: 1.2026x; 1.2026x over previous
//
#include <hip/hip_runtime.h>
#include <hip/hip_bf16.h>

#define B_ 32
#define S_ 64
#define H_ 300
#define H2_ 600
#define L_ 20
#define ROW_ 160                    // 8 pieces * 20
#define OUTQ_OFF ((size_t)B_ * S_ * ROW_)
#define NEG_INF -3.402823466e38f

// ---------------- K0: w^2 table [widx][l][h]
__global__ void k_w2(const float* __restrict__ Wf, float* __restrict__ w2) {
  int i = blockIdx.x * 256 + threadIdx.x;
  if (i < 8 * L_ * H_) { float v = Wf[i]; w2[i] = v * v; }
}

// ---------------- K1: plain cosine matrix per (b,dir) + fp64 row/col sums.
// thread t -> q=lane=t&63, p=(t>>6)+4k for k in [0,16).  (unchanged from r5 pass)
__global__ __launch_bounds__(256) void k_cos(const float* __restrict__ P,
                                             const float* __restrict__ Q,
                                             float* __restrict__ cosM,
                                             float* __restrict__ sum_p,
                                             float* __restrict__ sum_q) {
  int bd = blockIdx.x;
  int b = bd >> 1, dir = bd & 1;
  __shared__ float xp[S_][101];
  __shared__ float xq[S_][101];
  __shared__ float pn[S_], qn[S_];
  __shared__ float cosL[S_][S_ + 1];
  int t = threadIdx.x;
  int w = t >> 6, lane = t & 63;
  float dot[16];
#pragma unroll
  for (int k = 0; k < 16; ++k) dot[k] = 0.f;
  float np2 = 0.f, nq2 = 0.f;
  const float* Pb = P + (size_t)b * S_ * H2_ + dir * H_;
  const float* Qb = Q + (size_t)b * S_ * H2_ + dir * H_;
  for (int c0 = 0; c0 < H_; c0 += 100) {
    __syncthreads();
    for (int idx = t; idx < S_ * 100; idx += 256) {
      int s = idx / 100, hh = idx - s * 100;
      xp[s][hh] = Pb[(size_t)s * H2_ + c0 + hh];
      xq[s][hh] = Qb[(size_t)s * H2_ + c0 + hh];
    }
    __syncthreads();
    for (int hh = 0; hh < 100; ++hh) {
      float qv = xq[lane][hh];
#pragma unroll
      for (int k = 0; k < 16; ++k) dot[k] = fmaf(xp[w + 4 * k][hh], qv, dot[k]);
    }
    if (t < S_) {
      for (int hh = 0; hh < 100; ++hh) { float v = xp[t][hh]; np2 = fmaf(v, v, np2); }
    } else if (t < 2 * S_) {
      int s2 = t - S_;
      for (int hh = 0; hh < 100; ++hh) { float v = xq[s2][hh]; nq2 = fmaf(v, v, nq2); }
    }
  }
  if (t < S_) pn[t] = sqrtf(np2);
  else if (t < 2 * S_) qn[t - S_] = sqrtf(nq2);
  __syncthreads();
  float* cm = cosM + (size_t)bd * S_ * S_;
#pragma unroll
  for (int k = 0; k < 16; ++k) {
    int p = w + 4 * k;
    float c = dot[k] / (pn[p] * qn[lane]);   // no EPS in reference attentive cos
    cosL[p][lane] = c;
    cm[p * S_ + lane] = c;
  }
  __syncthreads();
  if (t < S_) {            // sum over p at q=t  (cos.sum(axis=1))
    double acc = 0.0;
    for (int p = 0; p < S_; ++p) acc += (double)cosL[p][t];
    sum_p[bd * S_ + t] = (float)acc;
  } else if (t < 2 * S_) { // sum over q at p=t-64  (cos.sum(axis=2))
    int r = t - S_;
    double acc = 0.0;
    for (int q = 0; q < S_; ++q) acc += (double)cosL[r][q];
    sum_q[bd * S_ + r] = (float)acc;
  }
}

// ---------------- K2: maxpool matching, one block per (b,dir,l) -> pieces 2,3.
// R6: 4x4 register tile (9 ds_read per 16 FMA instead of 18) + cosT aliased
// onto xp tile (LDS 56.8KB -> ~40KB: 4 blocks/CU instead of 2).
__global__ __launch_bounds__(256) void k_maxpool(const float* __restrict__ P,
                                                 const float* __restrict__ Q,
                                                 const float* __restrict__ w2,
                                                 float* __restrict__ out) {
  int l = blockIdx.x % L_;
  int bd = blockIdx.x / L_;
  int b = bd >> 1, dir = bd & 1;
  int t = threadIdx.x;
  int pi = t >> 4, qi = t & 15;
  __shared__ float xp[S_][75];    // 75: stride%32=11, conflict-free (r5: 0 conflicts)
  __shared__ float xq[S_][75];
  __shared__ float w2s[H_];
  __shared__ float pn[S_], qn[S_];
  float (*cosT)[S_ + 1] = (float (*)[S_ + 1])&xp[0][0];   // alias: 4160 <= 4800 floats
  const float* w2g = w2 + (size_t)(2 + dir) * L_ * H_ + (size_t)l * H_;
  for (int idx = t; idx < H_; idx += 256) w2s[idx] = w2g[idx];
  float dot[4][4] = {{0.f}};
  float np2 = 0.f, nq2 = 0.f;
  const float* Pb = P + (size_t)b * S_ * H2_ + dir * H_;
  const float* Qb = Q + (size_t)b * S_ * H2_ + dir * H_;
  for (int c0 = 0; c0 < H_; c0 += 75) {
    __syncthreads();
    for (int idx = t; idx < S_ * 75; idx += 256) {
      int s = idx / 75, hh = idx - s * 75;
      xp[s][hh] = Pb[(size_t)s * H2_ + c0 + hh];
      xq[s][hh] = Qb[(size_t)s * H2_ + c0 + hh];
    }
    __syncthreads();
    for (int hh = 0; hh < 75; ++hh) {
      float wv = w2s[c0 + hh];
      float pv[4], qv[4];
#pragma unroll
      for (int i = 0; i < 4; ++i) pv[i] = xp[4 * pi + i][hh] * wv;  // fold weight into p side
#pragma unroll
      for (int j = 0; j < 4; ++j) qv[j] = xq[4 * qi + j][hh];
#pragma unroll
      for (int i = 0; i < 4; ++i)
#pragma unroll
        for (int j = 0; j < 4; ++j) dot[i][j] = fmaf(pv[i], qv[j], dot[i][j]);
    }
    if (t < S_) {
      for (int hh = 0; hh < 75; ++hh) { float v = xp[t][hh]; np2 = fmaf(w2s[c0 + hh] * v, v, np2); }
    } else if (t < 2 * S_) {
      int s2 = t - S_;
      for (int hh = 0; hh < 75; ++hh) { float v = xq[s2][hh]; nq2 = fmaf(w2s[c0 + hh] * v, v, nq2); }
    }
  }
  if (t < S_) pn[t] = sqrtf(np2);
  else if (t < 2 * S_) qn[t - S_] = sqrtf(nq2);
  __syncthreads();   // also separates last xp read from cosT alias writes
#pragma unroll
  for (int i = 0; i < 4; ++i) {
    int p = 4 * pi + i;
#pragma unroll
    for (int j = 0; j < 4; ++j) {
      int q = 4 * qi + j;
      cosT[p][q] = dot[i][j] / (pn[p] * qn[q]);   // no EPS in reference maxpool
    }
  }
  __syncthreads();
  if (t < S_) {            // out_p[s=t] = max over q
    float m = NEG_INF;
    for (int q = 0; q < S_; ++q) m = fmaxf(m, cosT[t][q]);
    out[((size_t)b * S_ + t) * ROW_ + (2 + dir) * L_ + l] = m;
  } else if (t < 2 * S_) { // out_q[s] = max over p
    int s2 = t - S_;
    float m = NEG_INF;
    for (int p = 0; p < S_; ++p) m = fmaxf(m, cosT[p][s2]);
    out[OUTQ_OFF + ((size_t)b * S_ + s2) * ROW_ + (2 + dir) * L_ + l] = m;
  }
}

// ---------------- K3: FUSED attentive vectors + full/attentive outputs.
// One block per (bd, s). Attention vectors live only in LDS. (unchanged from r5 pass)
__global__ __launch_bounds__(256) void k_outs(const float* __restrict__ P,
                                              const float* __restrict__ Q,
                                              const float* __restrict__ w2,
                                              const float* __restrict__ cosM,
                                              const float* __restrict__ sum_p,
                                              const float* __restrict__ sum_q,
                                              float* __restrict__ out) {
  int bd = blockIdx.x >> 6;
  int s = blockIdx.x & 63;
  int b = bd >> 1, dir = bd & 1;
  int t = threadIdx.x;
  __shared__ float cosRow[S_];   // cos[s][q]
  __shared__ float cosCol[S_];   // cos[p][s]
  __shared__ float v8[8][H_];    // 0 xP, 1 xQ, 2 tQ, 3 tP, 4 qvm, 5 pvm, 6 qvx, 7 pvx
  __shared__ float sps, sqs;
  const float* cm = cosM + (size_t)bd * S_ * S_;
  if (t < S_) cosRow[t] = cm[s * S_ + t];
  else if (t < 2 * S_) cosCol[t - S_] = cm[(t - S_) * S_ + s];
  else if (t == 128) sps = sum_p[bd * S_ + s];   // sum over p of cos[p][s]
  else if (t == 129) sqs = sum_q[bd * S_ + s];   // sum over q of cos[s][q]
  int tgt = dir ? 0 : S_ - 1;
  const float* Pb = P + (size_t)b * S_ * H2_ + dir * H_;
  const float* Qb = Q + (size_t)b * S_ * H2_ + dir * H_;
  for (int idx = t; idx < 4 * H_; idx += 256) {
    int a = idx / H_, h = idx - a * H_;
    float v;
    switch (a) {
      case 0:  v = Pb[(size_t)s * H2_ + h]; break;
      case 1:  v = Qb[(size_t)s * H2_ + h]; break;
      case 2:  v = Qb[(size_t)tgt * H2_ + h]; break;
      default: v = Pb[(size_t)tgt * H2_ + h]; break;
    }
    v8[a][h] = v;
  }
  __syncthreads();
  // attention vectors for this s: qv* need cos row s, pv* need cos col s
  for (int h = t; h < H_; h += 256) {
    float am_p = 0.f, am_q = 0.f, ax_p = NEG_INF, ax_q = NEG_INF;
    for (int k = 0; k < S_; ++k) {
      float pv = Pb[(size_t)k * H2_ + h];
      float qv = Qb[(size_t)k * H2_ + h];
      float t1 = pv * cosCol[k];   // p_vec candidates at q=s
      am_p += t1; ax_p = fmaxf(ax_p, t1);
      float t2 = qv * cosRow[k];   // q_vec candidates at p=s
      am_q += t2; ax_q = fmaxf(ax_q, t2);
    }
    v8[4][h] = am_q / sqs;   // qvm = q_vec[p=s]
    v8[5][h] = am_p / sps;   // pvm = p_vec[q=s]
    v8[6][h] = ax_q;         // qvx
    v8[7][h] = ax_p;         // pvx
  }
  __syncthreads();
  if (t < 120) {
    int pr = t / L_, l = t - pr * L_;
    // pr: 0 p.tq W0  1 q.tp W0  2 p.qvm W4  3 q.pvm W4  4 p.qvx W6  5 q.pvx W6
    const int yi_[6] = {2, 3, 4, 5, 6, 7};
    const int wb_[6] = {0, 0, 4, 4, 6, 6};
    const float* x = v8[pr & 1];
    const float* y = v8[yi_[pr]];
    int widx = wb_[pr] + dir;
    const float* wp = w2 + (size_t)widx * (L_ * H_) + (size_t)l * H_;
    float a1 = 0.f, a2 = 0.f, a3 = 0.f;
    for (int h = 0; h < H_; ++h) {
      float wv = wp[h];
      float xx = x[h], yy = y[h];
      float wx = wv * xx;
      a1 = fmaf(wx, yy, a1);
      a2 = fmaf(wx, xx, a2);
      a3 = fmaf(wv * yy, yy, a3);
    }
    float den = fmaxf(sqrtf(a2) * sqrtf(a3), 1e-8f);   // EPS per _mp_cos
    float c = a1 / den;
    size_t base = ((pr & 1) ? OUTQ_OFF : 0) + ((size_t)b * S_ + s) * ROW_;
    out[base + (size_t)(wb_[pr] + dir) * L_ + l] = c;
  }
}

extern "C" void kernel_launch(void* const* d_in, const int* in_sizes, int n_in,
                              void* d_out, int out_size, void* d_ws, size_t ws_size,
                              hipStream_t stream) {
  (void)out_size; (void)ws_size;
  // W is the unique 48000-element input; p,q in dict order among the rest.
  int iw = 2;
  for (int i = 0; i < n_in; ++i) if (in_sizes[i] == 8 * L_ * H_) iw = i;
  int io[2] = {0, 1}, k = 0;
  for (int i = 0; i < n_in && k < 2; ++i) if (i != iw) io[k++] = i;
  const float* P  = (const float*)d_in[io[0]];
  const float* Q  = (const float*)d_in[io[1]];
  const float* Wf = (const float*)d_in[iw];
  float* out = (float*)d_out;   // reference output dtype is float32 -> float*

  float* ws = (float*)d_ws;     // 1.27 MB total
  float* w2    = ws;                // 48000
  float* cosM  = w2 + 48000;        // 262144
  float* sum_p = cosM + 262144;     // 4096
  float* sum_q = sum_p + 4096;      // 4096

  k_w2<<<(8 * L_ * H_ + 255) / 256, 256, 0, stream>>>(Wf, w2);
  k_cos<<<B_ * 2, 256, 0, stream>>>(P, Q, cosM, sum_p, sum_q);
  k_maxpool<<<B_ * 2 * L_, 256, 0, stream>>>(P, Q, w2, out);
  k_outs<<<B_ * 2 * S_, 256, 0, stream>>>(P, Q, w2, cosM, sum_p, sum_q, out);
}